// Round 4
// baseline (141.858 us; speedup 1.0000x reference)
//
#include <hip/hip_runtime.h>
#include <hip/hip_bf16.h>
#include <cstdint>
#include <cstddef>

#define NN 8192
#define FIN 256
#define FO 128

typedef float f32x4 __attribute__((ext_vector_type(4)));
typedef _Float16 f16x8 __attribute__((ext_vector_type(8)));

typedef __attribute__((address_space(3))) void lds_void;
typedef const __attribute__((address_space(1))) void glb_void;
__device__ __forceinline__ void gl_lds16(const void* g, void* l) {
  __builtin_amdgcn_global_load_lds((glb_void*)g, (lds_void*)l, 16, 0, 0);
}

__device__ __forceinline__ unsigned enc_f32(float f) {
  unsigned u = __float_as_uint(f);
  return (u & 0x80000000u) ? ~u : (u | 0x80000000u);
}
__device__ __forceinline__ float dec_f32(unsigned u) {
  unsigned b = (u & 0x80000000u) ? (u ^ 0x80000000u) : ~u;
  return __uint_as_float(b);
}

// ---------------- K0: compress adj (int32 0/1) -> row-major bitmask ------------
// One wave per row. Lane l reads adj[row][j0+l]: each instruction is a contiguous
// 256 B wave-granule, successive instructions walk the row sequentially -> full
// HBM streaming efficiency. Identity bit order: bit (j&63) of word[j>>6].
__global__ void __launch_bounds__(256) k0_bits(const int* __restrict__ adj,
                                               unsigned long long* __restrict__ bits) {
  int row = blockIdx.x * 4 + (threadIdx.x >> 6);
  int l = threadIdx.x & 63;
  const int* rowp = adj + (size_t)row * NN + l;
  unsigned long long* outp = bits + (size_t)row * (NN / 64);
#pragma unroll 2
  for (int j0 = 0; j0 < NN; j0 += 256) {
    int v0 = rowp[j0];
    int v1 = rowp[j0 + 64];
    int v2 = rowp[j0 + 128];
    int v3 = rowp[j0 + 192];
    unsigned long long m0 = __ballot(v0 > 0);
    unsigned long long m1 = __ballot(v1 > 0);
    unsigned long long m2 = __ballot(v2 > 0);
    unsigned long long m3 = __ballot(v3 > 0);
    if (l == 0) {
      outp[(j0 >> 6) + 0] = m0;
      outp[(j0 >> 6) + 1] = m1;
      outp[(j0 >> 6) + 2] = m2;
      outp[(j0 >> 6) + 3] = m3;
    }
  }
}

// ---------------- K1: h = x @ W  (8192x256 @ 256x128) ----------------
__global__ void k1_xw(const float* __restrict__ x, const float* __restrict__ W,
                      float* __restrict__ h, unsigned* __restrict__ enc) {
  __shared__ float xs[32 * 66];
  __shared__ float Ws[64 * 128];
  int t = threadIdx.x;
  int r0 = blockIdx.x * 32;
  if (blockIdx.x == 0 && t == 0) *enc = 0u;  // init for K2's atomicMax
  int r = t & 31, cg = t >> 5;
  float acc[16];
#pragma unroll
  for (int i = 0; i < 16; ++i) acc[i] = 0.f;
  for (int ko = 0; ko < 4; ++ko) {
    __syncthreads();
    {
      int rr = t >> 3, kc = (t & 7) * 8;
      const float2* src = (const float2*)(x + (size_t)(r0 + rr) * FIN + ko * 64 + kc);
      float2* dst = (float2*)&xs[rr * 66 + kc];
#pragma unroll
      for (int q = 0; q < 4; ++q) dst[q] = src[q];
    }
    {
      int kk = t >> 2, q = t & 3;
      const float4* src = (const float4*)(W + (size_t)(ko * 64 + kk) * FO + q * 32);
      float4* dst = (float4*)&Ws[kk * 128 + q * 32];
#pragma unroll
      for (int i = 0; i < 8; ++i) dst[i] = src[i];
    }
    __syncthreads();
#pragma unroll 8
    for (int kk = 0; kk < 64; ++kk) {
      float xv = xs[r * 66 + kk];
      const float4* wr = (const float4*)&Ws[kk * 128 + cg * 16];
      float4 w0 = wr[0], w1 = wr[1], w2 = wr[2], w3 = wr[3];
      acc[0]  = fmaf(xv, w0.x, acc[0]);  acc[1]  = fmaf(xv, w0.y, acc[1]);
      acc[2]  = fmaf(xv, w0.z, acc[2]);  acc[3]  = fmaf(xv, w0.w, acc[3]);
      acc[4]  = fmaf(xv, w1.x, acc[4]);  acc[5]  = fmaf(xv, w1.y, acc[5]);
      acc[6]  = fmaf(xv, w1.z, acc[6]);  acc[7]  = fmaf(xv, w1.w, acc[7]);
      acc[8]  = fmaf(xv, w2.x, acc[8]);  acc[9]  = fmaf(xv, w2.y, acc[9]);
      acc[10] = fmaf(xv, w2.z, acc[10]); acc[11] = fmaf(xv, w2.w, acc[11]);
      acc[12] = fmaf(xv, w3.x, acc[12]); acc[13] = fmaf(xv, w3.y, acc[13]);
      acc[14] = fmaf(xv, w3.z, acc[14]); acc[15] = fmaf(xv, w3.w, acc[15]);
    }
  }
  float* hp = h + (size_t)(r0 + r) * FO + cg * 16;
#pragma unroll
  for (int i = 0; i < 4; ++i)
    ((float4*)hp)[i] = make_float4(acc[4 * i], acc[4 * i + 1], acc[4 * i + 2], acc[4 * i + 3]);
}

// ---------------- K2: hT (fp16 transpose), s1, s2, max(s2) ----------------
__global__ void k2_prep(const float* __restrict__ h, const float* __restrict__ a,
                        _Float16* __restrict__ hT,
                        float* __restrict__ s1, float* __restrict__ s2,
                        unsigned* __restrict__ enc) {
  __shared__ float ht[64 * 129];
  int t = threadIdx.x;
  int r0 = blockIdx.x * 64;
  {
    int rr = t >> 2, q = t & 3;
    const float4* src = (const float4*)(h + (size_t)(r0 + rr) * FO + q * 32);
    float* dst = &ht[rr * 129 + q * 32];
#pragma unroll
    for (int i = 0; i < 8; ++i) {
      float4 v = src[i];
      dst[4 * i + 0] = v.x; dst[4 * i + 1] = v.y;
      dst[4 * i + 2] = v.z; dst[4 * i + 3] = v.w;
    }
  }
  __syncthreads();
  {
    int c = t >> 1, half = t & 1;
    alignas(16) _Float16 buf[32];
#pragma unroll
    for (int i = 0; i < 32; ++i) buf[i] = (_Float16)ht[(half * 32 + i) * 129 + c];
    int4* d = (int4*)(hT + (size_t)c * NN + r0 + half * 32);
#pragma unroll
    for (int i = 0; i < 4; ++i) d[i] = ((const int4*)buf)[i];
  }
  if (t < 64) {
    int row = r0 + t;
    float v1 = 0.f, v2 = 0.f;
#pragma unroll 16
    for (int c = 0; c < FO; ++c) {
      float hv = ht[t * 129 + c];
      v1 = fmaf(hv, a[c], v1);
      v2 = fmaf(hv, a[FO + c], v2);
    }
    s1[row] = v1; s2[row] = v2;
    float m = v2;
#pragma unroll
    for (int off = 1; off < 64; off <<= 1) m = fmaxf(m, __shfl_xor(m, off));
    if (t == 0) atomicMax(enc, enc_f32(m));
  }
}

// weight: w = bit ? exp(leaky(s1+s2) - m) : 0, rounded to fp16;
// den accumulates the *rounded* weight in f32 for exact normalization consistency.
__device__ __forceinline__ _Float16 wel(unsigned av, float s2v, float s1v, float mv, float& sum) {
  float tt = s1v + s2v;
  tt = fmaxf(tt, 0.01f * tt);  // leaky_relu
  float wf = av ? __expf(tt - mv) : 0.f;
  _Float16 wh = (_Float16)wf;
  sum += (float)wh;
  return wh;
}

// ---------------- K4: fused attention x h -------------------------------------
// grid (8 splits, 128 row-blocks), 256 threads = 4 waves x 16 rows.
// adj comes from the L3-resident bitmask (4 B/lane/iter instead of 32 B scattered).
// LDS: double-buffered 128x32 fp16 hT tile staged via global_load_lds (width 16).
// 2-phase counted-vmcnt pipeline: stage next -> compute -> vmcnt(4) -> s_barrier.
__global__ void __launch_bounds__(256, 4) k4_main(
    const unsigned* __restrict__ bits32, const float* __restrict__ s1g,
    const float* __restrict__ s2g, const unsigned* __restrict__ enc,
    const _Float16* __restrict__ hT,
    float* __restrict__ num_p, float* __restrict__ den_p, int jchunk) {
  __shared__ _Float16 tile[2][128 * 32];
  int t = threadIdx.x;
  int l = t & 63, wv = t >> 6;
  int l15 = l & 15, kgrp = l >> 4;
  int split = blockIdx.x;
  int r0 = blockIdx.y * 64;
  int jbeg = split * jchunk;
  int row = r0 + wv * 16 + l15;

  float c2 = dec_f32(*enc);
  float s10 = s1g[row];
  float m0 = s10 + c2; m0 = fmaxf(m0, 0.01f * m0);

  f32x4 acc[8];
#pragma unroll
  for (int cf = 0; cf < 8; ++cf) acc[cf] = (f32x4){0.f, 0.f, 0.f, 0.f};
  float sum0 = 0.f;
  const unsigned* bitsrow = bits32 + (size_t)row * (NN >> 5);

  auto stage = [&](int b, int j0) {
    const _Float16* g0 = hT + (size_t)(wv * 32 + (l >> 2)) * NN + j0 + (l & 3) * 8;
    gl_lds16(g0, &tile[b][(wv * 32) * 32]);
    gl_lds16(g0 + (size_t)16 * NN, &tile[b][(wv * 32 + 16) * 32]);
  };

  int niter = jchunk >> 5;
  // ---- prologue: stage buf0, prefetch iter0 bits/s2 ----
  stage(0, jbeg);
  __builtin_amdgcn_sched_barrier(0);
  int jl = jbeg + kgrp * 8;
  unsigned bw = bitsrow[jbeg >> 5];
  float4 sa = *(const float4*)(s2g + jl);
  float4 sb = *(const float4*)(s2g + jl + 4);
  asm volatile("s_waitcnt vmcnt(3)" ::: "memory");
  __builtin_amdgcn_s_barrier();
  __builtin_amdgcn_sched_barrier(0);

  int cur = 0;
  for (int tI = 0; tI < niter; ++tI) {
    int j0 = jbeg + (tI << 5);
    bool has_next = (tI + 1 < niter);
    if (has_next) stage(cur ^ 1, j0 + 32);
    __builtin_amdgcn_sched_barrier(0);
    unsigned nbw; float4 nsa, nsb;
    if (has_next) {
      int jn = j0 + 32 + kgrp * 8;
      nbw = bitsrow[(j0 + 32) >> 5];
      nsa = *(const float4*)(s2g + jn);
      nsb = *(const float4*)(s2g + jn + 4);
    }
    // attention weights, directly in A-fragment layout (row=l15, k=kgrp*8+e)
    unsigned byte = (bw >> (kgrp << 3)) & 0xffu;
    f16x8 af;
    af[0] = wel(byte & 1u,        sa.x, s10, m0, sum0);
    af[1] = wel(byte & 2u,        sa.y, s10, m0, sum0);
    af[2] = wel(byte & 4u,        sa.z, s10, m0, sum0);
    af[3] = wel(byte & 8u,        sa.w, s10, m0, sum0);
    af[4] = wel(byte & 16u,       sb.x, s10, m0, sum0);
    af[5] = wel(byte & 32u,       sb.y, s10, m0, sum0);
    af[6] = wel(byte & 64u,       sb.z, s10, m0, sum0);
    af[7] = wel(byte & 128u,      sb.w, s10, m0, sum0);
    // B fragments from LDS + MFMA
    f16x8 bfr[8];
#pragma unroll
    for (int cf = 0; cf < 8; ++cf)
      bfr[cf] = *(const f16x8*)&tile[cur][(cf * 16 + l15) * 32 + kgrp * 8];
#pragma unroll
    for (int cf = 0; cf < 8; ++cf)
      acc[cf] = __builtin_amdgcn_mfma_f32_16x16x32_f16(af, bfr[cf], acc[cf], 0, 0, 0);
    __builtin_amdgcn_sched_barrier(0);
    if (has_next) {
      asm volatile("s_waitcnt vmcnt(3)" ::: "memory");  // stage retired; bits/s2 stay in flight
      __builtin_amdgcn_s_barrier();
      __builtin_amdgcn_sched_barrier(0);
      bw = nbw; sa = nsa; sb = nsb;
      cur ^= 1;
    }
  }
  // row sums: lanes kgrp 0..3 of same l15 combine
  sum0 += __shfl_xor(sum0, 16);
  sum0 += __shfl_xor(sum0, 32);
  size_t sbase = (size_t)split * NN;
  if (l < 16) den_p[sbase + r0 + wv * 16 + l] = sum0;
  // C/D layout: col = l&15, row = kgrp*4 + i
#pragma unroll
  for (int cf = 0; cf < 8; ++cf) {
#pragma unroll
    for (int i = 0; i < 4; ++i) {
      int orow = r0 + wv * 16 + kgrp * 4 + i;
      int ocol = cf * 16 + l15;
      num_p[(sbase + orow) * (size_t)FO + ocol] = acc[cf][i];
    }
  }
}

// ---------------- K5: finalize out = elu(sum(num)/sum(den)) ----------------
__global__ void k5_fin(const float* __restrict__ num_p, const float* __restrict__ den_p,
                       float* __restrict__ out, int splitk) {
  int idx = blockIdx.x * 256 + threadIdx.x;
  int row = idx >> 7;
  float num = 0.f, den = 0.f;
  for (int s = 0; s < splitk; ++s) {
    num += num_p[(size_t)s * (NN * FO) + idx];
    den += den_p[(size_t)s * NN + row];
  }
  float v = num / den;
  out[idx] = v > 0.f ? v : expm1f(v);
}

extern "C" void kernel_launch(void* const* d_in, const int* in_sizes, int n_in,
                              void* d_out, int out_size, void* d_ws, size_t ws_size,
                              hipStream_t stream) {
  const float* x   = (const float*)d_in[0];
  const int*   adj = (const int*)d_in[1];
  const float* W   = (const float*)d_in[2];
  const float* a   = (const float*)d_in[3];
  float* out = (float*)d_out;
  char* ws = (char*)d_ws;

  float*     h     = (float*)ws;                                   // 4 MB
  _Float16*  hT    = (_Float16*)(ws + ((size_t)4 << 20));          // 2 MB
  float*     s1    = (float*)(ws + ((size_t)6 << 20));             // 32 KB
  float*     s2    = (float*)(ws + ((size_t)6 << 20) + (32u << 10));
  unsigned*  enc   = (unsigned*)(ws + ((size_t)6 << 20) + (64u << 10));
  float*     den_p = (float*)(ws + ((size_t)6 << 20) + (128u << 10)); // 256 KB max
  float*     num_p = (float*)(ws + ((size_t)7 << 20));             // splitk * 4 MB
  unsigned long long* bits = (unsigned long long*)(ws + ((size_t)40 << 20)); // 8.4 MB

  int splitk = 8;
  while (splitk > 1 &&
         ((size_t)48 << 20) + ((size_t)1 << 20) > ws_size)
    splitk >>= 1;
  int jchunk = NN / splitk;

  k0_bits<<<dim3(NN / 4), dim3(256), 0, stream>>>(adj, bits);
  k1_xw<<<dim3(256), dim3(256), 0, stream>>>(x, W, h, enc);
  k2_prep<<<dim3(128), dim3(256), 0, stream>>>(h, a, hT, s1, s2, enc);
  k4_main<<<dim3(splitk, 128), dim3(256), 0, stream>>>((const unsigned*)bits, s1, s2, enc, hT,
                                                       num_p, den_p, jchunk);
  k5_fin<<<dim3((NN * FO) / 256), dim3(256), 0, stream>>>(num_p, den_p, out, splitk);
}